// Round 2
// baseline (122.157 us; speedup 1.0000x reference)
//
#include <hip/hip_runtime.h>

// RandomDropout: B=8192 rows, S=2048 cols, int32 tokens.
// Odd rows with n_tokens>=10: drop argmin(uniform(key(42))) position among
// first n_tokens, compact left, zero tail. Else: passthrough.
//
// PRNG_VARIANT journal (flip on absmax ~3.2e4 failure):
//   0 = partitionable threefry, out0                     [R0: FAILED 31992]
//   1 = partitionable threefry, out0 ^ out1 (jax prng.py bits1^bits2)  <- R1
//   2 = original split scheme: i<half -> out0(i, i+half); else out1(i-half, i)
//   3 = partitionable, out1 (low-word truncate)
#define PRNG_VARIANT 1

constexpr int S = 2048;
constexpr int BLOCK = 256;
constexpr int PER_THREAD = S / BLOCK; // 8

__device__ __forceinline__ unsigned rotl32(unsigned x, int r) {
    return (x << r) | (x >> (32 - r));
}

// Threefry-2x32, 20 rounds, key = (0, 42)  [jax.random.key(42)]
__device__ __forceinline__ void threefry2x32_k42(unsigned c0, unsigned c1,
                                                 unsigned& o0, unsigned& o1) {
    const unsigned ks0 = 0u;
    const unsigned ks1 = 42u;
    const unsigned ks2 = 0x1BD11BDAu ^ ks0 ^ ks1; // 0x1BD11BF0
    unsigned x0 = c0 + ks0;
    unsigned x1 = c1 + ks1;
#define TF_R4(a, b, c, d)                                   \
    x0 += x1; x1 = rotl32(x1, a); x1 ^= x0;                 \
    x0 += x1; x1 = rotl32(x1, b); x1 ^= x0;                 \
    x0 += x1; x1 = rotl32(x1, c); x1 ^= x0;                 \
    x0 += x1; x1 = rotl32(x1, d); x1 ^= x0;
    TF_R4(13, 15, 26, 6)   x0 += ks1; x1 += ks2 + 1u;
    TF_R4(17, 29, 16, 24)  x0 += ks2; x1 += ks0 + 2u;
    TF_R4(13, 15, 26, 6)   x0 += ks0; x1 += ks1 + 3u;
    TF_R4(17, 29, 16, 24)  x0 += ks1; x1 += ks2 + 4u;
    TF_R4(13, 15, 26, 6)   x0 += ks2; x1 += ks0 + 5u;
#undef TF_R4
    o0 = x0;
    o1 = x1;
}

__device__ __forceinline__ unsigned prng_bits(unsigned flat_idx, unsigned half) {
    unsigned o0, o1;
#if PRNG_VARIANT == 0
    threefry2x32_k42(0u, flat_idx, o0, o1);
    return o0;
#elif PRNG_VARIANT == 1
    threefry2x32_k42(0u, flat_idx, o0, o1);
    return o0 ^ o1;
#elif PRNG_VARIANT == 3
    threefry2x32_k42(0u, flat_idx, o0, o1);
    return o1;
#else
    if (flat_idx < half) {
        threefry2x32_k42(flat_idx, flat_idx + half, o0, o1);
        return o0;
    } else {
        threefry2x32_k42(flat_idx - half, flat_idx, o0, o1);
        return o1;
    }
#endif
}

__global__ __launch_bounds__(BLOCK) void random_dropout_kernel(
    const int* __restrict__ in, int* __restrict__ out, unsigned half_total) {
    __shared__ int row[S];
    __shared__ int wcnt[BLOCK / 64];
    __shared__ unsigned long long wmin[BLOCK / 64];
    __shared__ int s_ntok;
    __shared__ int s_drop;

    const int b = blockIdx.x;
    const size_t base = (size_t)b * S;
    const int4* vin = (const int4*)(in + base);
    int4* vout = (int4*)(out + base);
    const int tid = threadIdx.x;

    // Stage row: vectorized load -> registers + LDS; count positives.
    int4 v[2];
    int cnt = 0;
#pragma unroll
    for (int k = 0; k < 2; k++) {
        v[k] = vin[tid + k * BLOCK];
        ((int4*)row)[tid + k * BLOCK] = v[k];
        cnt += (v[k].x > 0) + (v[k].y > 0) + (v[k].z > 0) + (v[k].w > 0);
    }
    // Block reduction for n_tokens (4 waves).
#pragma unroll
    for (int off = 32; off; off >>= 1) cnt += __shfl_down(cnt, off, 64);
    if ((tid & 63) == 0) wcnt[tid >> 6] = cnt;
    __syncthreads();
    if (tid == 0) s_ntok = wcnt[0] + wcnt[1] + wcnt[2] + wcnt[3];
    __syncthreads();
    const int ntok = s_ntok;
    const bool apply = (b & 1) && (ntok >= 10);

    if (!apply) {
        // Passthrough from registers (no PRNG work, no second sync needed).
#pragma unroll
        for (int k = 0; k < 2; k++) vout[tid + k * BLOCK] = v[k];
        return;
    }

    // Argmin of uniform over s in [0, ntok). Uniform's float value is
    // monotone in (bits >> 9); pack (mant23 << 11 | s) for lowest-index ties.
    unsigned long long best = ~0ull;
    for (int k = 0; k < PER_THREAD; k++) {
        const int s = tid + k * BLOCK;
        if (s >= ntok) break;
        const unsigned i = (unsigned)(b * S + s);
        const unsigned bits = prng_bits(i, half_total);
        const unsigned long long comb =
            ((unsigned long long)(bits >> 9) << 11) | (unsigned)s;
        best = comb < best ? comb : best;
    }
#pragma unroll
    for (int off = 32; off; off >>= 1) {
        const unsigned long long o = __shfl_down(best, off, 64);
        best = o < best ? o : best;
    }
    if ((tid & 63) == 0) wmin[tid >> 6] = best;
    __syncthreads();
    if (tid == 0) {
        unsigned long long m = wmin[0];
        m = wmin[1] < m ? wmin[1] : m;
        m = wmin[2] < m ? wmin[2] : m;
        m = wmin[3] < m ? wmin[3] : m;
        s_drop = (int)(m & 0x7FFull);
    }
    __syncthreads();
    const int drop = s_drop;

    // Shifted write: out[j] = in[j] (j<drop) | in[j+1] (drop<=j<ntok-1) | 0.
#pragma unroll
    for (int k = 0; k < 2; k++) {
        const int j4 = tid + k * BLOCK;
        const int jb = j4 * 4;
        int4 o;
        int* op = (int*)&o;
#pragma unroll
        for (int c = 0; c < 4; c++) {
            const int j = jb + c;
            int val;
            if (j < drop) val = row[j];
            else if (j < ntok - 1) val = row[j + 1];
            else val = 0;
            op[c] = val;
        }
        vout[j4] = o;
    }
}

extern "C" void kernel_launch(void* const* d_in, const int* in_sizes, int n_in,
                              void* d_out, int out_size, void* d_ws, size_t ws_size,
                              hipStream_t stream) {
    const int* in = (const int*)d_in[0];
    int* out = (int*)d_out;
    const int total = in_sizes[0];          // B * S
    const int B = total / S;                // 8192
    const unsigned half_total = (unsigned)(total / 2);
    random_dropout_kernel<<<B, BLOCK, 0, stream>>>(in, out, half_total);
}

// Round 3
// 117.987 us; speedup vs baseline: 1.0353x; 1.0353x over previous
//
#include <hip/hip_runtime.h>

// RandomDropout: B=8192 rows, S=2048 cols, int32 tokens.
// Odd rows with n_tokens>=10: drop argmin(uniform(key(42))) among first
// n_tokens, compact left, zero tail. Else: passthrough.
//
// PRNG: JAX partitionable threefry (confirmed R1): bits(i) =
//   threefry2x32(key=(0,42), c0=0, c1=i).out0 ^ .out1
//
// R2 design: ONE ROW PER WAVE. 64 lanes x 32 elems (8 int4, strided
// ownership g = lane + 64k for perfect coalescing). Zero barriers, zero
// LDS. Shift-by-one via __shfl_down of each chunk's .x; zero tail comes
// free from the input's prefix-zero property (in[j+1]==0 for j>=ntok-1).

constexpr int S = 2048;
constexpr int BLOCK = 256;           // 4 waves
constexpr int ROWS_PER_BLOCK = 4;    // 1 row per wave
constexpr int CHUNKS = S / 4 / 64;   // 8 int4 per lane

__device__ __forceinline__ unsigned rotl32(unsigned x, int r) {
    return (x << r) | (x >> (32 - r));
}

// Threefry-2x32, 20 rounds, key = (0, 42); returns out0 ^ out1.
__device__ __forceinline__ unsigned prng_bits(unsigned flat_idx) {
    const unsigned ks0 = 0u;
    const unsigned ks1 = 42u;
    const unsigned ks2 = 0x1BD11BDAu ^ ks0 ^ ks1;
    unsigned x0 = 0u + ks0;
    unsigned x1 = flat_idx + ks1;
#define TF_R4(a, b, c, d)                                   \
    x0 += x1; x1 = rotl32(x1, a); x1 ^= x0;                 \
    x0 += x1; x1 = rotl32(x1, b); x1 ^= x0;                 \
    x0 += x1; x1 = rotl32(x1, c); x1 ^= x0;                 \
    x0 += x1; x1 = rotl32(x1, d); x1 ^= x0;
    TF_R4(13, 15, 26, 6)   x0 += ks1; x1 += ks2 + 1u;
    TF_R4(17, 29, 16, 24)  x0 += ks2; x1 += ks0 + 2u;
    TF_R4(13, 15, 26, 6)   x0 += ks0; x1 += ks1 + 3u;
    TF_R4(17, 29, 16, 24)  x0 += ks1; x1 += ks2 + 4u;
    TF_R4(13, 15, 26, 6)   x0 += ks2; x1 += ks0 + 5u;
#undef TF_R4
    return x0 ^ x1;
}

__global__ __launch_bounds__(BLOCK) void random_dropout_kernel(
    const int* __restrict__ in, int* __restrict__ out) {
    const int wave = threadIdx.x >> 6;
    const int lane = threadIdx.x & 63;
    const int b = blockIdx.x * ROWS_PER_BLOCK + wave;
    const size_t base = (size_t)b * S;
    const int4* vin = (const int4*)(in + base);
    int4* vout = (int4*)(out + base);

    // Load 8 int4, strided (int4 index g = lane + 64k): perfectly coalesced.
    int4 v[CHUNKS];
    int cnt = 0;
#pragma unroll
    for (int k = 0; k < CHUNKS; k++) {
        v[k] = vin[lane + 64 * k];
        cnt += (v[k].x > 0) + (v[k].y > 0) + (v[k].z > 0) + (v[k].w > 0);
    }
    // Wave-local sum -> ntok (broadcast from lane 0).
#pragma unroll
    for (int off = 32; off; off >>= 1) cnt += __shfl_down(cnt, off, 64);
    const int ntok = __shfl(cnt, 0, 64);

    const bool apply = (b & 1) && (ntok >= 10);
    if (!apply) {
#pragma unroll
        for (int k = 0; k < CHUNKS; k++) vout[lane + 64 * k] = v[k];
        return;
    }

    // Argmin of uniform over s in [0, ntok), strided by 64 across lanes.
    // uniform value is monotone in (bits >> 9); pack (mant23<<11 | s) so
    // ties break to the lowest index (matches stable top_k).
    unsigned long long best = ~0ull;
    const unsigned rowbase = (unsigned)b * (unsigned)S;
    for (int s = lane; s < ntok; s += 64) {
        const unsigned bits = prng_bits(rowbase + (unsigned)s);
        const unsigned long long comb =
            ((unsigned long long)(bits >> 9) << 11) | (unsigned)s;
        best = comb < best ? comb : best;
    }
#pragma unroll
    for (int off = 32; off; off >>= 1) {
        const unsigned long long o = __shfl_down(best, off, 64);
        best = o < best ? o : best;
    }
    const unsigned long long m = __shfl(best, 0, 64);
    const int drop = (int)(m & 0x7FFull);

    // Successor of each int4's last element: element 4*(g+1).
    //   lanes 0..62: lane+1's v[k].x ; lane 63: lane 0's v[k+1].x ;
    //   lane 63 chunk 7: element 2048 -> 0.
    int nx[CHUNKS];
#pragma unroll
    for (int k = 0; k < CHUNKS; k++) {
        const int a = __shfl_down(v[k].x, 1, 64);
        const int bb = (k < CHUNKS - 1) ? __shfl(v[k + 1].x, 0, 64) : 0;
        nx[k] = (lane == 63) ? bb : a;
    }

    // out[j] = j < drop ? in[j] : in[j+1]  (tail zeros come free: the
    // input's prefix-zero property gives in[j+1]==0 for j >= ntok-1).
#pragma unroll
    for (int k = 0; k < CHUNKS; k++) {
        const int j0 = 4 * (lane + 64 * k);
        int4 o;
        o.x = (j0 + 0 < drop) ? v[k].x : v[k].y;
        o.y = (j0 + 1 < drop) ? v[k].y : v[k].z;
        o.z = (j0 + 2 < drop) ? v[k].z : v[k].w;
        o.w = (j0 + 3 < drop) ? v[k].w : nx[k];
        vout[lane + 64 * k] = o;
    }
}

extern "C" void kernel_launch(void* const* d_in, const int* in_sizes, int n_in,
                              void* d_out, int out_size, void* d_ws, size_t ws_size,
                              hipStream_t stream) {
    const int* in = (const int*)d_in[0];
    int* out = (int*)d_out;
    const int total = in_sizes[0];               // B * S
    const int B = total / S;                     // 8192
    random_dropout_kernel<<<B / ROWS_PER_BLOCK, BLOCK, 0, stream>>>(in, out);
}

// Round 4
// 116.806 us; speedup vs baseline: 1.0458x; 1.0101x over previous
//
#include <hip/hip_runtime.h>

// RandomDropout: B=8192 rows, S=2048 cols, int32 tokens.
// Odd rows with n_tokens>=10: drop argmin(uniform(key(42))) among first
// n_tokens, compact left, zero tail. Else: passthrough.
//
// PRNG: JAX partitionable threefry (confirmed R1): bits(i) =
//   threefry2x32(key=(0,42), c0=0, c1=i).out0 ^ .out1
//
// R3 design:
//  - No token count at all: ntok>=10 <=> in[row,9] > 0 (prefix property),
//    and the argmin mask "s < ntok" <=> "token > 0". Removes the 6-step
//    sum reduce and its serialization against the stores.
//  - Homogeneous blocks: first half of grid = even rows (pure streaming
//    copy), second half = odd rows (threefry+shift). Even blocks retire
//    fast and free CU slots instead of idling behind threefry waves.
//  - __launch_bounds__(256,8): pin 8 waves/SIMD (VGPR cap 64; odd path
//    ~50 live). R2 history: barriers/LDS removed in R2 (122->118 us).

constexpr int S = 2048;
constexpr int BLOCK = 256;           // 4 waves; 1 row per wave
constexpr int CHUNKS = S / 4 / 64;   // 8 int4 per lane

__device__ __forceinline__ unsigned rotl32(unsigned x, int r) {
    return (x << r) | (x >> (32 - r));
}

// Threefry-2x32, 20 rounds, key = (0, 42); returns out0 ^ out1.
__device__ __forceinline__ unsigned prng_bits(unsigned flat_idx) {
    const unsigned ks0 = 0u;
    const unsigned ks1 = 42u;
    const unsigned ks2 = 0x1BD11BDAu ^ ks0 ^ ks1;
    unsigned x0 = 0u + ks0;
    unsigned x1 = flat_idx + ks1;
#define TF_R4(a, b, c, d)                                   \
    x0 += x1; x1 = rotl32(x1, a); x1 ^= x0;                 \
    x0 += x1; x1 = rotl32(x1, b); x1 ^= x0;                 \
    x0 += x1; x1 = rotl32(x1, c); x1 ^= x0;                 \
    x0 += x1; x1 = rotl32(x1, d); x1 ^= x0;
    TF_R4(13, 15, 26, 6)   x0 += ks1; x1 += ks2 + 1u;
    TF_R4(17, 29, 16, 24)  x0 += ks2; x1 += ks0 + 2u;
    TF_R4(13, 15, 26, 6)   x0 += ks0; x1 += ks1 + 3u;
    TF_R4(17, 29, 16, 24)  x0 += ks1; x1 += ks2 + 4u;
    TF_R4(13, 15, 26, 6)   x0 += ks2; x1 += ks0 + 5u;
#undef TF_R4
    return x0 ^ x1;
}

__global__ __launch_bounds__(BLOCK, 8) void random_dropout_kernel(
    const int* __restrict__ in, int* __restrict__ out) {
    const int wave = threadIdx.x >> 6;
    const int lane = threadIdx.x & 63;
    const int nb_even = (int)(gridDim.x >> 1);
    const bool odd_block = (int)blockIdx.x >= nb_even;

    // Homogeneous row mapping: even blocks -> even rows, odd -> odd rows.
    const int slot = odd_block ? ((int)blockIdx.x - nb_even) : (int)blockIdx.x;
    const int b = 2 * (4 * slot + wave) + (odd_block ? 1 : 0);
    const size_t base = (size_t)b * S;
    const int4* vin = (const int4*)(in + base);
    int4* vout = (int4*)(out + base);

    if (!odd_block) {
        // Pure streaming copy: no counts, no reductions, stores independent.
#pragma unroll
        for (int k = 0; k < CHUNKS; k++) {
            const int4 t = vin[lane + 64 * k];
            vout[lane + 64 * k] = t;
        }
        return;
    }

    // Odd row: load all chunks (independent, all in flight).
    int4 v[CHUNKS];
#pragma unroll
    for (int k = 0; k < CHUNKS; k++) v[k] = vin[lane + 64 * k];

    // apply <=> ntok >= 10 <=> in[row,9] > 0. Position 9 = 4*2+1 -> lane 2,
    // chunk 0, component .y.
    const bool apply = __shfl(v[0].y, 2, 64) > 0;

    if (!apply) {
#pragma unroll
        for (int k = 0; k < CHUNKS; k++) vout[lane + 64 * k] = v[k];
        return;
    }

    // Argmin of uniform over valid positions (token > 0 <=> s < ntok).
    // uniform value is monotone in (bits >> 9); pack (mant23<<11 | s) so
    // ties break to the lowest index (matches stable top_k).
    unsigned long long best = ~0ull;
    const unsigned rowbase = (unsigned)b * (unsigned)S;
#pragma unroll
    for (int k = 0; k < CHUNKS; k++) {
        const int s0 = 4 * (lane + 64 * k);
        const int* e = (const int*)&v[k];
#pragma unroll
        for (int c = 0; c < 4; c++) {
            if (e[c] > 0) {
                const unsigned bits = prng_bits(rowbase + (unsigned)(s0 + c));
                const unsigned long long comb =
                    ((unsigned long long)(bits >> 9) << 11) |
                    (unsigned)(s0 + c);
                best = comb < best ? comb : best;
            }
        }
    }
#pragma unroll
    for (int off = 32; off; off >>= 1) {
        const unsigned long long o = __shfl_down(best, off, 64);
        best = o < best ? o : best;
    }
    const int drop = (int)(__shfl(best, 0, 64) & 0x7FFull);

    // Successor of each int4's last element (element 4*(g+1)):
    //   lanes 0..62: lane+1's v[k].x ; lane 63: lane 0's v[k+1].x ;
    //   lane 63 chunk 7: element 2048 -> 0.
    int nx[CHUNKS];
#pragma unroll
    for (int k = 0; k < CHUNKS; k++) {
        const int a = __shfl_down(v[k].x, 1, 64);
        const int bb = (k < CHUNKS - 1) ? __shfl(v[k + 1].x, 0, 64) : 0;
        nx[k] = (lane == 63) ? bb : a;
    }

    // out[j] = j < drop ? in[j] : in[j+1]  (tail zeros free: prefix-zero
    // input gives in[j+1]==0 for j >= ntok-1).
#pragma unroll
    for (int k = 0; k < CHUNKS; k++) {
        const int j0 = 4 * (lane + 64 * k);
        int4 o;
        o.x = (j0 + 0 < drop) ? v[k].x : v[k].y;
        o.y = (j0 + 1 < drop) ? v[k].y : v[k].z;
        o.z = (j0 + 2 < drop) ? v[k].z : v[k].w;
        o.w = (j0 + 3 < drop) ? v[k].w : nx[k];
        vout[lane + 64 * k] = o;
    }
}

extern "C" void kernel_launch(void* const* d_in, const int* in_sizes, int n_in,
                              void* d_out, int out_size, void* d_ws, size_t ws_size,
                              hipStream_t stream) {
    const int* in = (const int*)d_in[0];
    int* out = (int*)d_out;
    const int total = in_sizes[0];               // B * S
    const int B = total / S;                     // 8192
    random_dropout_kernel<<<B / 4, BLOCK, 0, stream>>>(in, out);
}